// Round 6
// baseline (144.963 us; speedup 1.0000x reference)
//
#include <hip/hip_runtime.h>

// Hierarchical softmax: B=4096, NHID=512, BR=32, DEPTH=3, V=32768.
// bucket g = lab>>5. node0=0 (step g>>5), node1=1+(g>>5) (step g&31),
// node2=33+g (step lab&31). out[b] = prod_k softmax(x_b @ W[node_k])[step_k]
//
// R6: sort kernel emits node2-uniform GROUPS (start, m<=8, bucket) of the
// sorted order. One block per group; 4 waves = 4 h-quarters; each wave runs
// ONE barrier-free 16-iter stream loading w0/w1/w2 (unroll-8 => ~24 loads in
// flight) and FMAs against 8 samples' x (split conflict-free LDS layout).
// Logical W traffic 768 MB -> ~200 MB, attacking the measured ~25 B/cyc/CU
// vector-memory wall while keeping R5's wave count.

#define NHID  512
#define BR    32
#define BATCH 4096
#define NBUCK 1024
#define GMAX  2048
#define SMAX  8

#define FMA4(A, xv, wv_) do { \
    (A).x = fmaf((xv), (wv_).x, (A).x); \
    (A).y = fmaf((xv), (wv_).y, (A).y); \
    (A).z = fmaf((xv), (wv_).z, (A).z); \
    (A).w = fmaf((xv), (wv_).w, (A).w); } while (0)

// ---------- single-block counting sort + group descriptors ----------
__global__ __launch_bounds__(1024) void k_sort(const int* __restrict__ labels,
                                               int* __restrict__ order,
                                               int* __restrict__ ngroups,
                                               int* __restrict__ gdesc) {
    __shared__ int labs[BATCH];   // 16 KB
    __shared__ int hist[NBUCK];   // 4 KB (offset -> cursor)
    __shared__ int scn[NBUCK];    // 4 KB
    __shared__ int desc[GMAX];    // 8 KB
    __shared__ int ng;
    const int t = threadIdx.x;

    if (t == 0) ng = 0;
    hist[t] = 0;
    #pragma unroll
    for (int r = 0; r < BATCH / 1024; ++r)
        labs[t + 1024 * r] = labels[t + 1024 * r];
    __syncthreads();
    #pragma unroll
    for (int r = 0; r < BATCH / 1024; ++r)
        atomicAdd(&hist[labs[t + 1024 * r] >> 5], 1);
    __syncthreads();

    const int cnt = hist[t];
    scn[t] = cnt;
    __syncthreads();
    for (int d = 1; d < NBUCK; d <<= 1) {
        int u = (t >= d) ? scn[t - d] : 0;
        __syncthreads();
        scn[t] += u;
        __syncthreads();
    }
    const int off = scn[t] - cnt;   // exclusive offset
    hist[t] = off;                  // becomes scatter cursor

    // emit descriptors for bucket t: (start | m<<12 | bucket<<16)
    for (int j = 0; j < cnt; j += SMAX) {
        int p = atomicAdd(&ng, 1);
        desc[p] = (off + j) | (min(SMAX, cnt - j) << 12) | (t << 16);
    }
    __syncthreads();

    #pragma unroll
    for (int r = 0; r < BATCH / 1024; ++r) {
        int j = t + 1024 * r;
        int pos = atomicAdd(&hist[labs[j] >> 5], 1);
        order[pos] = j;
    }
    const int n = ng;
    if (t == 0) *ngroups = n;
    for (int p = t; p < n; p += 1024) gdesc[p] = desc[p];
}

// ---------- compute: one block per node2-uniform group ----------
__global__ __launch_bounds__(256) void hsm_groups(
    const float* __restrict__ inputs,
    const int* __restrict__ labels,
    const float* __restrict__ W,
    const int* __restrict__ order,
    const int* __restrict__ ngroups,
    const int* __restrict__ gdesc,
    float* __restrict__ out)
{
    __shared__ float xsA[NHID * 4];            // 8 KB  [h][s0..3]
    __shared__ float xsB[NHID * 4];            // 8 KB  [h][s4..7]
    __shared__ float partial[4 * 3 * SMAX * BR]; // 12 KB [q][k][s][col]
    __shared__ float pk[3][SMAX];
    __shared__ int   sids[SMAX];
    __shared__ int   slab[SMAX];

    const int gid = blockIdx.x;
    if (gid >= *ngroups) return;
    const int d     = gdesc[gid];
    const int start = d & 0xFFF;
    const int m     = (d >> 12) & 0xF;
    const int g     = d >> 16;
    const int tid   = threadIdx.x;

    if (tid < SMAX) {
        int sid = (tid < m) ? order[start + tid] : -1;
        sids[tid] = sid;
        slab[tid] = (sid >= 0) ? labels[sid] : 0;
    }
    __syncthreads();

    // ---- stage x: xsA[h][s0..3], xsB[h][s4..7], zero-padded ----
    #pragma unroll
    for (int r = 0; r < 2; ++r) {
        int h = tid + 256 * r;
        float va[4], vb[4];
        #pragma unroll
        for (int s = 0; s < 4; ++s) {
            int ida = sids[s];
            int idb = sids[s + 4];
            va[s] = (ida >= 0) ? inputs[(size_t)ida * NHID + h] : 0.0f;
            vb[s] = (idb >= 0) ? inputs[(size_t)idb * NHID + h] : 0.0f;
        }
        ((float4*)xsA)[h] = make_float4(va[0], va[1], va[2], va[3]);
        ((float4*)xsB)[h] = make_float4(vb[0], vb[1], vb[2], vb[3]);
    }
    __syncthreads();

    const int q    = tid >> 6;    // wave = h-quarter
    const int lane = tid & 63;
    const int colg = lane & 7;    // float4 column group
    const int hsel = lane >> 3;   // h strip (h = 128q + 8i + hsel)

    const int node1 = 1 + (g >> 5);
    const int node2 = 33 + g;

    // float4-unit offset for (row h = 128q + 8i + hsel, col 4*colg)
    const size_t laneoff = (size_t)q * 1024 + (size_t)hsel * 8 + colg;
    const float4* wp0 = (const float4*)W + laneoff;
    const float4* wp1 = (const float4*)(W + (size_t)node1 * (NHID * BR)) + laneoff;
    const float4* wp2 = (const float4*)(W + (size_t)node2 * (NHID * BR)) + laneoff;
    const float4* xa4 = (const float4*)xsA + q * 128 + hsel;
    const float4* xb4 = (const float4*)xsB + q * 128 + hsel;

    float4 acc[3][SMAX];
    #pragma unroll
    for (int k = 0; k < 3; ++k)
        #pragma unroll
        for (int s = 0; s < SMAX; ++s) acc[k][s] = make_float4(0, 0, 0, 0);

    #pragma unroll 8
    for (int i = 0; i < 16; ++i) {
        float4 w0 = wp0[i * 64];
        float4 w1 = wp1[i * 64];
        float4 w2 = wp2[i * 64];
        float4 xa = xa4[i * 8];    // samples 0..3 at this h (broadcast)
        float4 xb = xb4[i * 8];    // samples 4..7
        FMA4(acc[0][0], xa.x, w0); FMA4(acc[0][1], xa.y, w0);
        FMA4(acc[0][2], xa.z, w0); FMA4(acc[0][3], xa.w, w0);
        FMA4(acc[0][4], xb.x, w0); FMA4(acc[0][5], xb.y, w0);
        FMA4(acc[0][6], xb.z, w0); FMA4(acc[0][7], xb.w, w0);
        FMA4(acc[1][0], xa.x, w1); FMA4(acc[1][1], xa.y, w1);
        FMA4(acc[1][2], xa.z, w1); FMA4(acc[1][3], xa.w, w1);
        FMA4(acc[1][4], xb.x, w1); FMA4(acc[1][5], xb.y, w1);
        FMA4(acc[1][6], xb.z, w1); FMA4(acc[1][7], xb.w, w1);
        FMA4(acc[2][0], xa.x, w2); FMA4(acc[2][1], xa.y, w2);
        FMA4(acc[2][2], xa.z, w2); FMA4(acc[2][3], xa.w, w2);
        FMA4(acc[2][4], xb.x, w2); FMA4(acc[2][5], xb.y, w2);
        FMA4(acc[2][6], xb.z, w2); FMA4(acc[2][7], xb.w, w2);
    }

    // butterfly-reduce over hsel (masks 8,16,32); lanes 0..7 end complete
    #pragma unroll
    for (int k = 0; k < 3; ++k) {
        #pragma unroll
        for (int s = 0; s < SMAX; ++s) {
            #pragma unroll
            for (int mm = 8; mm <= 32; mm <<= 1) {
                acc[k][s].x += __shfl_xor(acc[k][s].x, mm);
                acc[k][s].y += __shfl_xor(acc[k][s].y, mm);
                acc[k][s].z += __shfl_xor(acc[k][s].z, mm);
                acc[k][s].w += __shfl_xor(acc[k][s].w, mm);
            }
        }
    }
    if (lane < 8) {   // colg == lane
        #pragma unroll
        for (int k = 0; k < 3; ++k)
            #pragma unroll
            for (int s = 0; s < SMAX; ++s)
                *(float4*)&partial[(((q * 3) + k) * SMAX + s) * BR + lane * 4]
                    = acc[k][s];
    }
    __syncthreads();

    // ---- reducer + softmax: 256 threads = (s, col) ----
    {
        int s   = tid >> 5;
        int col = tid & 31;
        #pragma unroll
        for (int k = 0; k < 3; ++k) {
            float l = 0.0f;
            #pragma unroll
            for (int qq = 0; qq < 4; ++qq)
                l += partial[(((qq * 3) + k) * SMAX + s) * BR + col];
            float mx = l;
            #pragma unroll
            for (int mm = 1; mm <= 16; mm <<= 1)
                mx = fmaxf(mx, __shfl_xor(mx, mm));
            float e  = expf(l - mx);
            float es = e;
            #pragma unroll
            for (int mm = 1; mm <= 16; mm <<= 1)
                es += __shfl_xor(es, mm);
            int step = (k == 0) ? (g >> 5)
                     : (k == 1) ? (g & 31)
                                : (slab[s] & 31);
            if (col == step) pk[k][s] = e / es;
        }
    }
    __syncthreads();

    if (tid < m) {
        out[sids[tid]] = pk[0][tid] * pk[1][tid] * pk[2][tid];
    }
}

extern "C" void kernel_launch(void* const* d_in, const int* in_sizes, int n_in,
                              void* d_out, int out_size, void* d_ws, size_t ws_size,
                              hipStream_t stream)
{
    const float* inputs = (const float*)d_in[0];
    const int*   labels = (const int*)d_in[1];
    const float* W      = (const float*)d_in[2];
    float* out = (float*)d_out;

    char* ws = (char*)d_ws;
    int* order   = (int*)ws;               // 16 KB
    int* ngroups = (int*)(ws + 16384);     // 4 B
    int* gdesc   = (int*)(ws + 16384 + 128); // 8 KB

    k_sort    <<<dim3(1),    dim3(1024), 0, stream>>>(labels, order, ngroups, gdesc);
    hsm_groups<<<dim3(GMAX), dim3(256),  0, stream>>>(inputs, labels, W, order,
                                                      ngroups, gdesc, out);
}

// Round 7
// 122.718 us; speedup vs baseline: 1.1813x; 1.1813x over previous
//
#include <hip/hip_runtime.h>

// Hierarchical softmax: B=4096, NHID=512, BR=32, DEPTH=3, V=32768.
// bucket g = lab>>5. node0=0 (step g>>5), node1=1+(g>>5) (step g&31),
// node2=33+g (step lab&31). out[b] = prod_k softmax(x_b @ W[node_k])[step_k]
//
// R7: node2-uniform groups of SMAX=4 samples, but the compute block keeps
// R5's PROVEN issue shape: 192 threads, wave k = level k, one uninterrupted
// 64-iteration coalesced float4 W-stream per wave, accumulators only 16 VGPR.
// Logical W traffic 768 MB -> ~284 MB on the machine that demonstrated
// 15 TB/s logical streaming in R1/R5. Sort emits descriptors in bucket
// order (second scan, no atomics).

#define NHID  512
#define BR    32
#define BATCH 4096
#define NBUCK 1024
#define SMAX  4
#define GMAX  2048   // >= worst-case groups (<= 1792)

#define FMA4(A, xv, wv_) do { \
    (A).x = fmaf((xv), (wv_).x, (A).x); \
    (A).y = fmaf((xv), (wv_).y, (A).y); \
    (A).z = fmaf((xv), (wv_).z, (A).z); \
    (A).w = fmaf((xv), (wv_).w, (A).w); } while (0)

// ---------- single-block counting sort + ordered group descriptors ----------
__global__ __launch_bounds__(1024) void k_sort(const int* __restrict__ labels,
                                               int* __restrict__ order,
                                               int* __restrict__ ngroups,
                                               int* __restrict__ gdesc) {
    __shared__ int labs[BATCH];   // 16 KB
    __shared__ int hist[NBUCK];   // 4 KB (offset -> cursor)
    __shared__ int scn[NBUCK];    // 4 KB (sample scan)
    __shared__ int gsc[NBUCK];    // 4 KB (group scan)
    const int t = threadIdx.x;

    hist[t] = 0;
    #pragma unroll
    for (int r = 0; r < BATCH / 1024; ++r)
        labs[t + 1024 * r] = labels[t + 1024 * r];
    __syncthreads();
    #pragma unroll
    for (int r = 0; r < BATCH / 1024; ++r)
        atomicAdd(&hist[labs[t + 1024 * r] >> 5], 1);
    __syncthreads();

    const int cnt  = hist[t];
    const int gcnt = (cnt + SMAX - 1) / SMAX;
    scn[t] = cnt;
    gsc[t] = gcnt;
    __syncthreads();
    for (int d = 1; d < NBUCK; d <<= 1) {
        int u1 = (t >= d) ? scn[t - d] : 0;
        int u2 = (t >= d) ? gsc[t - d] : 0;
        __syncthreads();
        scn[t] += u1;
        gsc[t] += u2;
        __syncthreads();
    }
    const int off  = scn[t] - cnt;    // exclusive sample offset
    const int goff = gsc[t] - gcnt;   // exclusive group offset
    hist[t] = off;                    // becomes scatter cursor

    // ordered descriptors: (start | m<<12 | bucket<<16)
    for (int j = 0; j < gcnt; ++j)
        gdesc[goff + j] = (off + j * SMAX)
                        | (min(SMAX, cnt - j * SMAX) << 12)
                        | (t << 16);
    if (t == NBUCK - 1) *ngroups = gsc[t];
    __syncthreads();

    #pragma unroll
    for (int r = 0; r < BATCH / 1024; ++r) {
        int j = t + 1024 * r;
        int pos = atomicAdd(&hist[labs[j] >> 5], 1);
        order[pos] = j;
    }
}

// ---------- compute: one block per group, R5 shape (3 waves = 3 levels) ----------
__global__ __launch_bounds__(192) void hsm_g4(
    const float* __restrict__ inputs,
    const int* __restrict__ labels,
    const float* __restrict__ W,
    const int* __restrict__ order,
    const int* __restrict__ ngroups,
    const int* __restrict__ gdesc,
    float* __restrict__ out)
{
    __shared__ float xsT[NHID * SMAX];   // 8 KB, xsT[h][s0..3]
    __shared__ float pk[3][SMAX];
    __shared__ int   sids[SMAX];
    __shared__ int   slab[SMAX];

    const int gid = blockIdx.x;
    if (gid >= *ngroups) return;
    const int d     = gdesc[gid];
    const int start = d & 0xFFF;
    const int m     = (d >> 12) & 0xF;
    const int g     = d >> 16;
    const int tid   = threadIdx.x;

    if (tid < SMAX) {
        int sid = (tid < m) ? order[start + tid] : -1;
        sids[tid] = sid;
        slab[tid] = (sid >= 0) ? labels[sid] : 0;
    }
    __syncthreads();

    // ---- stage xsT[h][s] (16 B rows -> distinct bank quads, conflict-free) ----
    for (int h = tid; h < NHID; h += 192) {
        float v[SMAX];
        #pragma unroll
        for (int s = 0; s < SMAX; ++s) {
            int id = sids[s];
            v[s] = (id >= 0) ? inputs[(size_t)id * NHID + h] : 0.0f;
        }
        ((float4*)xsT)[h] = make_float4(v[0], v[1], v[2], v[3]);
    }
    __syncthreads();

    const int k    = tid >> 6;    // wave = tree level
    const int lane = tid & 63;
    const int colg = lane & 7;    // float4 column group
    const int hsel = lane >> 3;   // h strip: h = 8i + hsel

    const int node = (k == 0) ? 0 : (k == 1) ? 1 + (g >> 5) : 33 + g;
    const int step01 = (k == 0) ? (g >> 5) : (g & 31);

    const float4* wp = (const float4*)(W + (size_t)node * (NHID * BR))
                       + hsel * 8 + colg;
    const float4* xp = (const float4*)xsT + hsel;

    float4 acc[SMAX];
    #pragma unroll
    for (int s = 0; s < SMAX; ++s) acc[s] = make_float4(0, 0, 0, 0);

    // one uninterrupted coalesced stream: 64 x (1 KB/wave) loads
    #pragma unroll 8
    for (int i = 0; i < 64; ++i) {
        float4 w  = wp[i * 64];    // row 8i+hsel, cols 4*colg..
        float4 x4 = xp[i * 8];     // xsT[8i+hsel][0..3] (broadcast to 8 lanes)
        FMA4(acc[0], x4.x, w);
        FMA4(acc[1], x4.y, w);
        FMA4(acc[2], x4.z, w);
        FMA4(acc[3], x4.w, w);
    }

    // butterfly-reduce over hsel (masks 8,16,32): all lanes get full sums
    #pragma unroll
    for (int s = 0; s < SMAX; ++s) {
        #pragma unroll
        for (int mm = 8; mm <= 32; mm <<= 1) {
            acc[s].x += __shfl_xor(acc[s].x, mm);
            acc[s].y += __shfl_xor(acc[s].y, mm);
            acc[s].z += __shfl_xor(acc[s].z, mm);
            acc[s].w += __shfl_xor(acc[s].w, mm);
        }
    }

    // per-sample softmax over 32 logits (8 colg lanes x 4 comps)
    #pragma unroll
    for (int s = 0; s < SMAX; ++s) {
        float4 a = acc[s];
        float mx = fmaxf(fmaxf(a.x, a.y), fmaxf(a.z, a.w));
        #pragma unroll
        for (int mm = 1; mm <= 4; mm <<= 1) mx = fmaxf(mx, __shfl_xor(mx, mm));
        float es = expf(a.x - mx) + expf(a.y - mx) + expf(a.z - mx) + expf(a.w - mx);
        #pragma unroll
        for (int mm = 1; mm <= 4; mm <<= 1) es += __shfl_xor(es, mm);

        int step = (k == 2) ? (slab[s] & 31) : step01;
        int e = step & 3;
        float v = (e == 0) ? a.x : (e == 1) ? a.y : (e == 2) ? a.z : a.w;
        float sl = __shfl(v, step >> 2);
        float p = expf(sl - mx) / es;
        if (lane == 0) pk[k][s] = p;
    }
    __syncthreads();

    if (tid < SMAX && sids[tid] >= 0)
        out[sids[tid]] = pk[0][tid] * pk[1][tid] * pk[2][tid];
}

extern "C" void kernel_launch(void* const* d_in, const int* in_sizes, int n_in,
                              void* d_out, int out_size, void* d_ws, size_t ws_size,
                              hipStream_t stream)
{
    const float* inputs = (const float*)d_in[0];
    const int*   labels = (const int*)d_in[1];
    const float* W      = (const float*)d_in[2];
    float* out = (float*)d_out;

    char* ws = (char*)d_ws;
    int* order   = (int*)ws;                  // 16 KB
    int* ngroups = (int*)(ws + 16384);        // 4 B (padded to 128)
    int* gdesc   = (int*)(ws + 16384 + 128);  // 8 KB

    k_sort<<<dim3(1),    dim3(1024), 0, stream>>>(labels, order, ngroups, gdesc);
    hsm_g4<<<dim3(GMAX), dim3(192),  0, stream>>>(inputs, labels, W, order,
                                                  ngroups, gdesc, out);
}